// Round 12
// baseline (223.777 us; speedup 1.0000x reference)
//
#include <hip/hip_runtime.h>

#define NMEM 16384
#define MDIM 225
#define L1D 134
#define MCLS 4489     // 67*67 real positions per class
#define PPAD 4608     // 144*32 padded positions
#define NTILE2 512    // 256 tiles * 2 surfaced candidates
#define MARGIN 0.5f

typedef __attribute__((ext_vector_type(8))) _Float16 f16x8;
typedef __attribute__((ext_vector_type(16))) float f32x16;

__device__ inline unsigned short f2h(float f) {
    const _Float16 h = (_Float16)f;
    unsigned short u; __builtin_memcpy(&u, &h, 2); return u;
}
__device__ inline _Float16 us2h(unsigned short u) {
    _Float16 h; __builtin_memcpy(&h, &u, 2); return h;
}
__device__ inline float h2f(unsigned short u) { return (float)us2h(u); }

// ---------------------------------------------------------------------------
// P0 (fused, R7-measured-best): blocks [0,4096): one WAVE per n. Wave stages
// the 225-float mem row in LDS once (coalesced float4), then lane k reads the
// 9-point LDS neighborhood covering ALL 4 classes' collapsed taps. Sums use
// the ORIGINAL association order (zero-padded invalid taps) -> bit-identical
// cmh; hn uses the original strided order -> bit-identical hn/hnb.
// Blocks [4096,4240): X positions in B-fragment fp16 layout.
// ---------------------------------------------------------------------------
__global__ __launch_bounds__(256) void prep_fused(const float* __restrict__ mem,
                                                  const float* __restrict__ img,
                                                  unsigned short* __restrict__ cmh,
                                                  float* __restrict__ hn,
                                                  unsigned int* __restrict__ hnb,
                                                  unsigned short* __restrict__ xh) {
    if (blockIdx.x >= 4096) {
        // ---- prep_x body ----
        const int t = (blockIdx.x - 4096) * 256 + threadIdx.x;   // 36864
        const int nl = t & 31, g = (t >> 5) & 1, ks = (t >> 6) & 3, pt = t >> 8;
        const int pos = pt * 32 + nl;
        const int u = ks * 2 + g;
        unsigned short h[8];
        if (pos < MCLS) {
            const int mr = pos / 67, mc = pos - mr * 67;
            const int r = mr - 5 + u;
            #pragma unroll
            for (int j = 0; j < 8; ++j) {
                const int c = mc - 5 + j;
                float v = 0.f;
                if ((unsigned)r < 64u && (unsigned)c < 64u) v = img[r * 64 + c];
                h[j] = f2h(v);
            }
        } else {
            #pragma unroll
            for (int j = 0; j < 8; ++j) h[j] = 0;
        }
        #pragma unroll
        for (int j = 0; j < 8; ++j) xh[(size_t)t * 8 + j] = h[j];
        return;
    }

    // ---- prep_cm body: one wave per n ----
    __shared__ float rowbuf[4][240];
    const int wave = threadIdx.x >> 6, lane = threadIdx.x & 63;
    const int n = blockIdx.x * 4 + wave;
    const float* mrow = mem + (size_t)n * MDIM;

    if (lane < 56) {
        const float4 v4 = *(const float4*)(mrow + lane * 4);
        *(float4*)(&rowbuf[wave][lane * 4]) = v4;
    } else if (lane == 56) {
        rowbuf[wave][224] = mrow[224];
    }
    // Same-wave LDS write->read: compiler inserts the lgkmcnt wait.

    const float* rb = rowbuf[wave];
    float q = 0.f;
    for (int t2 = lane; t2 < MDIM; t2 += 64) { const float v2 = rb[t2]; q += v2 * v2; }
    #pragma unroll
    for (int m = 1; m < 64; m <<= 1) q += __shfl_xor(q, m);
    if (lane == 0) {
        const float h = 0.5f * q;
        hn[n] = h;
        const unsigned short nh = f2h(-h);
        const unsigned short nl2 = f2h(-h - h2f(nh));
        hnb[n] = (unsigned)nh | ((unsigned)nl2 << 16);
    }

    const int k = lane, u = k >> 3, v = k & 7;
    const int ir = 2 * u, ic = 2 * v;
    float g9[3][3];
    #pragma unroll
    for (int di = -1; di <= 1; ++di) {
        #pragma unroll
        for (int dj = -1; dj <= 1; ++dj) {
            const int i = ir + di, j = ic + dj;
            g9[di + 1][dj + 1] = ((unsigned)i < 15u && (unsigned)j < 15u)
                                     ? rb[i * 15 + j] : 0.f;
        }
    }
    #pragma unroll
    for (int er = 0; er < 2; ++er) {
        #pragma unroll
        for (int ec = 0; ec < 2; ++ec) {
            const int cls = er * 2 + ec;
            float s = 0.f;
            s += g9[1 - er][1 - ec];
            s += g9[1 - er][2 - ec];
            s += g9[2 - er][1 - ec];
            s += g9[2 - er][2 - ec];
            cmh[((size_t)(cls * NMEM + n)) * 64 + k] = f2h(s);
        }
    }
}

// ---------------------------------------------------------------------------
// K1 (R10-exact, measured plateau 76.4-78.3us across 7 variants): fp16
// single-product MFMA scoring. Grid (256 nblk, 4 cls), 4 waves,
// __launch_bounds__(256,4). A (64 n x 64 k) register-resident; -hn folded via
// fp16 hi/lo ext K-slice. B single-buffered (16 regs), prefetched right after
// MFMAs consume them (xh is L2-hot). No LDS, no barriers. Top-2 via
// v_med3_f32 + hoisted idv table; cross-half merge via __shfl_xor.
//
// CLOSED LEVERS (all measured): op-count cuts neutral (R4); permlane slower
// (R6); (256,5) spills (R9: FETCH 395MB); +32-reg f32 C-init spills (R3:
// FETCH 610MB); z-split neutral (R8); phase stagger null (R11). This exact
// structure at (256,4) is the operating point.
//
// nblk XCD-write-merge swizzle: (bx&7)*32 + (bx>>3) -> same-XCD blocks own
// consecutive nblk so 8B float2 stores merge into full 64B lines in L2
// (verified R0->R1: WRITE_SIZE 158MB -> 36.9MB).
// A/B frag: row=lane&31, k=(lane>>5)*8+j. C/D: col=lane&31,
// row=(r&3)+8*(r>>2)+4*(lane>>5)  [HW-verified].
// ---------------------------------------------------------------------------
__global__ __launch_bounds__(256, 4) void mfma_argmin_kernel(const unsigned short* __restrict__ cmh,
                                                             const unsigned short* __restrict__ xh,
                                                             const unsigned int* __restrict__ hnb,
                                                             float* __restrict__ pcvT) {
    const int nblk = ((blockIdx.x & 7) << 5) | (blockIdx.x >> 3);   // XCD write-merge swizzle
    const int cls = blockIdx.y;
    const int t = threadIdx.x, wave = t >> 6, lane = t & 63;
    const int g = lane >> 5, nl = lane & 31;

    // One-time A fragment loads (row nl and nl+32, all 4 K-slices).
    f16x8 a0[4], a1[4];
    #pragma unroll
    for (int ks = 0; ks < 4; ++ks) {
        const size_t base = ((size_t)(cls * NMEM + nblk * 64 + nl)) * 64 + ks * 16 + g * 8;
        a0[ks] = *(const f16x8*)(cmh + base);
        a1[ks] = *(const f16x8*)(cmh + base + 32 * 64);
    }

    // hn-folding ext slice: A_ext=(-hn_hi,-hn_lo,0..), B_ext=(1,1,0..).
    const unsigned int hp0 = hnb[nblk * 64 + nl];
    const unsigned int hp1 = hnb[nblk * 64 + 32 + nl];
    f16x8 aex0 = {0,0,0,0,0,0,0,0}, aex1 = {0,0,0,0,0,0,0,0}, bex = {0,0,0,0,0,0,0,0};
    if (g == 0) {
        aex0[0] = us2h((unsigned short)(hp0 & 0xFFFFu));
        aex0[1] = us2h((unsigned short)(hp0 >> 16));
        aex1[0] = us2h((unsigned short)(hp1 & 0xFFFFu));
        aex1[1] = us2h((unsigned short)(hp1 >> 16));
        bex[0] = (_Float16)1.0f;
        bex[1] = (_Float16)1.0f;
    }

    // Hoisted id table: 16 VGPRs, loop-invariant.
    int idv[16];
    #pragma unroll
    for (int r = 0; r < 16; ++r) idv[r] = (r & 3) + 8 * (r >> 2) + 4 * g;

    // B pointer for this wave/g: pt = it*4+wave  =>  +8192 halves per iter.
    const unsigned short* xp = xh + ((size_t)((wave * 4) * 2 + g)) * 256 + nl * 8;

    // Store pointer: pos = (it*4+wave)*32 + nl advances 128/iter => +65536 f.
    float* stp = pcvT + ((size_t)(cls * PPAD + wave * 32 + nl)) * NTILE2 + nblk * 2;

    f16x8 b[4];
    #pragma unroll
    for (int ks = 0; ks < 4; ++ks) b[ks] = *(const f16x8*)(xp + ks * 512);

    for (int it = 0; it < 36; ++it) {
        f32x16 acc0 = {0.f,0.f,0.f,0.f,0.f,0.f,0.f,0.f,0.f,0.f,0.f,0.f,0.f,0.f,0.f,0.f};
        f32x16 acc1 = {0.f,0.f,0.f,0.f,0.f,0.f,0.f,0.f,0.f,0.f,0.f,0.f,0.f,0.f,0.f,0.f};
        __builtin_amdgcn_s_setprio(1);
        #pragma unroll
        for (int ks = 0; ks < 4; ++ks) {
            acc0 = __builtin_amdgcn_mfma_f32_32x32x16_f16(a0[ks], b[ks], acc0, 0, 0, 0);
            acc1 = __builtin_amdgcn_mfma_f32_32x32x16_f16(a1[ks], b[ks], acc1, 0, 0, 0);
        }
        acc0 = __builtin_amdgcn_mfma_f32_32x32x16_f16(aex0, bex, acc0, 0, 0, 0);
        acc1 = __builtin_amdgcn_mfma_f32_32x32x16_f16(aex1, bex, acc1, 0, 0, 0);
        __builtin_amdgcn_s_setprio(0);

        // Prefetch next B into the SAME registers (WAR-safe: MFMAs above
        // already consumed b). Epilogue below hides the load latency.
        xp += 8192;
        if (it < 35) {
            #pragma unroll
            for (int ks = 0; ks < 4; ++ks) b[ks] = *(const f16x8*)(xp + ks * 512);
        }

        // Exact top-2 insert: m2 = med3(m1_old, m2_old, v); m1 = max(m1_old, v).
        float m1 = -3.0e38f, m2 = -3.0e38f;
        #pragma unroll
        for (int r = 0; r < 16; ++r) {
            const float v = __int_as_float((__float_as_int(acc0[r]) & ~63) | idv[r]);
            m2 = __builtin_amdgcn_fmed3f(m1, m2, v);
            m1 = fmaxf(m1, v);
        }
        #pragma unroll
        for (int r = 0; r < 16; ++r) {
            const float w = __int_as_float(((__float_as_int(acc1[r]) & ~63) | idv[r]) | 32);
            m2 = __builtin_amdgcn_fmed3f(m1, m2, w);
            m1 = fmaxf(m1, w);
        }

        const float o1 = __shfl_xor(m1, 32);
        const float o2 = __shfl_xor(m2, 32);
        const float M1 = fmaxf(m1, o1);
        const float M2 = fmaxf(fminf(m1, o1), fmaxf(m2, o2));

        if (g == 0) {
            float2 st; st.x = M1; st.y = M2;
            *(float2*)stp = st;
        }
        stp += (size_t)128 * NTILE2;
    }
}

// ---------------------------------------------------------------------------
// K2: rescue, one wave per (cls, pos). Singleton fast-path (R8): tot==1
// recovers the winner directly from the packed 6-bit id (no mem reads, no
// reduces) — output identical. tot>=2 falls to the pair-pipelined
// exact-rescore loop.
// ---------------------------------------------------------------------------
__global__ __launch_bounds__(256) void rescue_kernel(const float* __restrict__ img,
                                                     const float* __restrict__ mem,
                                                     const float* __restrict__ hn,
                                                     const float* __restrict__ pcvT,
                                                     int* __restrict__ idx2d) {
    const int wave = threadIdx.x >> 6, lane = threadIdx.x & 63;
    const int cls = blockIdx.y;
    const int pos = blockIdx.x * 4 + wave;
    if (pos >= MCLS) return;
    const int er = cls >> 1, ec = cls & 1;
    const int mr = pos / 67, mc = pos - mr * 67;

    const float* row = pcvT + ((size_t)(cls * PPAD + pos)) * NTILE2 + lane * 8;
    const float4 v0 = *(const float4*)row;
    const float4 v1 = *(const float4*)(row + 4);
    float vals[8] = {v0.x, v0.y, v0.z, v0.w, v1.x, v1.y, v1.z, v1.w};

    float vmax = vals[0];
    #pragma unroll
    for (int s = 1; s < 8; ++s) vmax = fmaxf(vmax, vals[s]);
    #pragma unroll
    for (int m = 1; m < 64; m <<= 1) vmax = fmaxf(vmax, __shfl_xor(vmax, m));
    const float thr = vmax - MARGIN;

    unsigned long long bals[8];
    int tot = 0;
    #pragma unroll
    for (int s = 0; s < 8; ++s) {
        bals[s] = __ballot(vals[s] >= thr);
        tot += __popcll(bals[s]);
    }

    int bn = 0x7FFFFFFF;
    if (tot == 1) {
        float cv = -3.0e38f; int cs = 0;
        #pragma unroll
        for (int s = 0; s < 8; ++s)
            if (vals[s] >= thr) { cv = vals[s]; cs = s; }
        unsigned long long ba = 0;
        #pragma unroll
        for (int s = 0; s < 8; ++s) ba |= bals[s];
        const int src = __ffsll((long long)ba) - 1;
        const float pv = __shfl(cv, src);
        const int ss = __shfl(cs, src);
        bn = (((src * 8 + ss) >> 1) << 6) | (__float_as_int(pv) & 63);
    } else {
        const int xr = mr - 5 + (lane >> 3), xc = mc - 5 + (lane & 7);
        const float xv = ((unsigned)xr < 64u && (unsigned)xc < 64u) ? img[xr * 64 + xc] : 0.f;
        float xt[4];
        #pragma unroll
        for (int q = 0; q < 4; ++q) {
            const int tt = q * 64 + lane;
            const int a = tt / 15, b = tt - 15 * a;
            const int xi = (((a + er) >> 1) & 7) * 8 + (((b + ec) >> 1) & 7);
            xt[q] = __shfl(xv, xi);
        }

        float best = -3.0e38f;
        #pragma unroll
        for (int s = 0; s < 8; ++s) {
            unsigned long long bal = bals[s];
            while (bal) {
                const int src0 = __ffsll((long long)bal) - 1;
                bal &= bal - 1;
                int src1 = -1;
                if (bal) { src1 = __ffsll((long long)bal) - 1; bal &= bal - 1; }
                const float pv0 = __shfl(vals[s], src0);
                const float pv1 = __shfl(vals[s], src1 < 0 ? src0 : src1);
                const int n0 = (((src0 * 8 + s) >> 1) << 6) | (__float_as_int(pv0) & 63);
                const int n1 = ((((src1 < 0 ? src0 : src1) * 8 + s) >> 1) << 6) | (__float_as_int(pv1) & 63);
                const float* mrow0 = mem + (size_t)n0 * MDIM;
                const float* mrow1 = mem + (size_t)n1 * MDIM;
                float p0 = 0.f, p1 = 0.f;
                #pragma unroll
                for (int q = 0; q < 4; ++q) {
                    const int tt = q * 64 + lane;
                    if (tt < MDIM) {
                        p0 = fmaf(mrow0[tt], xt[q], p0);
                        p1 = fmaf(mrow1[tt], xt[q], p1);
                    }
                }
                #pragma unroll
                for (int m = 1; m < 64; m <<= 1) {
                    p0 += __shfl_xor(p0, m);
                    p1 += __shfl_xor(p1, m);
                }
                const float sc0 = p0 - hn[n0];
                if (sc0 > best || (sc0 == best && n0 < bn)) { best = sc0; bn = n0; }
                if (src1 >= 0) {
                    const float sc1 = p1 - hn[n1];
                    if (sc1 > best || (sc1 == best && n1 < bn)) { best = sc1; bn = n1; }
                }
            }
        }
    }
    if (lane == 0) idx2d[(er + 2 * mr) * L1D + (ec + 2 * mc)] = bn;
}

// ---------------------------------------------------------------------------
// K3+K4 merged (R12): fold, one wave per output pixel; the LAST block to
// finish (device-scope atomic counter, zeroed via hipMemsetAsync each launch)
// runs the norm body. __threadfence() before the atomic publishes outraw
// stores device-wide; the fence after re-acquires them (classic last-block
// pattern, XCD-safe per G16: device-scope atomics + fences). amLast is
// block-uniform (shared, set by thread 0, read after __syncthreads), so the
// norm body's internal __syncthreads is non-divergent. Saves one launch.
// ---------------------------------------------------------------------------
__global__ __launch_bounds__(256) void fold_norm_kernel(const float* __restrict__ mem,
                                                        const int* __restrict__ idx2d,
                                                        float* __restrict__ outraw,
                                                        float* __restrict__ out,
                                                        int* __restrict__ counter) {
    const int wave = threadIdx.x >> 6, lane = threadIdx.x & 63;
    const int p = blockIdx.x * 4 + wave;   // 0..4095
    const int oi = p >> 6, oj = p & 63;
    float s = 0.f;
    #pragma unroll
    for (int tb = 0; tb < 256; tb += 64) {
        const int tt = tb + lane;
        if (tt < MDIM) {
            const int a = tt / 15, b = tt - 15 * a;
            const int r = 10 + 2 * oi - a, c = 10 + 2 * oj - b;
            if ((unsigned)r < (unsigned)L1D && (unsigned)c < (unsigned)L1D) {
                const int n = idx2d[r * L1D + c];
                s += mem[(size_t)n * MDIM + tt];
            }
        }
    }
    #pragma unroll
    for (int msk = 1; msk < 64; msk <<= 1) s += __shfl_xor(s, msk);
    if (lane == 0) outraw[p] = s;

    // ---- last-block norm ----
    __threadfence();                       // publish outraw stores device-wide
    __shared__ int amLast;
    if (threadIdx.x == 0) amLast = (atomicAdd(counter, 1) == (int)gridDim.x - 1);
    __syncthreads();
    if (amLast) {
        __threadfence();                   // acquire all blocks' outraw stores
        __shared__ float red[256];
        const int t = threadIdx.x;
        float m = -3.0e38f;
        #pragma unroll
        for (int i = 0; i < 16; ++i) m = fmaxf(m, outraw[t + i * 256]);
        red[t] = m;
        __syncthreads();
        for (int ss = 128; ss > 0; ss >>= 1) {
            if (t < ss) red[t] = fmaxf(red[t], red[t + ss]);
            __syncthreads();
        }
        const float mx = red[0];
        #pragma unroll
        for (int i = 0; i < 16; ++i) out[t + i * 256] = outraw[t + i * 256] / mx;
    }
}

extern "C" void kernel_launch(void* const* d_in, const int* in_sizes, int n_in,
                              void* d_out, int out_size, void* d_ws, size_t ws_size,
                              hipStream_t stream) {
    const float* img = (const float*)d_in[0];   // 64*64 fp32
    const float* mem = (const float*)d_in[1];   // 16384*225 fp32
    float* out = (float*)d_out;                 // 4096 fp32

    unsigned short* cmh = (unsigned short*)d_ws;              // 4*16384*64 ushort = 8.4 MB
    float* hn = (float*)(cmh + (size_t)4 * NMEM * 64);        // 16384 f
    unsigned int* hnb = (unsigned int*)(hn + NMEM);           // 16384 u32
    unsigned short* xh = (unsigned short*)(hnb + NMEM);       // 294912 ushort
    float* pcvT = (float*)(xh + 294912);                      // 4*4608*512 f = 37.7 MB
    int* idx2d = (int*)(pcvT + (size_t)4 * PPAD * NTILE2);    // 17956 i
    float* outraw = (float*)(idx2d + L1D * L1D);              // 4096 f
    int* counter = (int*)(outraw + 4096);                     // 1 i

    hipMemsetAsync(counter, 0, sizeof(int), stream);
    prep_fused<<<4096 + 144, 256, 0, stream>>>(mem, img, cmh, hn, hnb, xh);
    mfma_argmin_kernel<<<dim3(256, 4), 256, 0, stream>>>(cmh, xh, hnb, pcvT);
    rescue_kernel<<<dim3((MCLS + 3) / 4, 4), 256, 0, stream>>>(img, mem, hn, pcvT, idx2d);
    fold_norm_kernel<<<1024, 256, 0, stream>>>(mem, idx2d, outraw, out, counter);
}

// Round 13
// 152.627 us; speedup vs baseline: 1.4662x; 1.4662x over previous
//
#include <hip/hip_runtime.h>

#define NMEM 16384
#define MDIM 225
#define L1D 134
#define MCLS 4489     // 67*67 real positions per class
#define PPAD 4608     // 144*32 padded positions
#define NTILE2 512    // 256 tiles * 2 surfaced candidates
#define MARGIN 0.5f

typedef __attribute__((ext_vector_type(8))) _Float16 f16x8;
typedef __attribute__((ext_vector_type(16))) float f32x16;

__device__ inline unsigned short f2h(float f) {
    const _Float16 h = (_Float16)f;
    unsigned short u; __builtin_memcpy(&u, &h, 2); return u;
}
__device__ inline _Float16 us2h(unsigned short u) {
    _Float16 h; __builtin_memcpy(&h, &u, 2); return h;
}
__device__ inline float h2f(unsigned short u) { return (float)us2h(u); }

// ---------------------------------------------------------------------------
// P0 (fused, R7-measured-best): blocks [0,4096): one WAVE per n. Wave stages
// the 225-float mem row in LDS once (coalesced float4), then lane k reads the
// 9-point LDS neighborhood covering ALL 4 classes' collapsed taps. Sums use
// the ORIGINAL association order (zero-padded invalid taps) -> bit-identical
// cmh; hn uses the original strided order -> bit-identical hn/hnb.
// Blocks [4096,4240): X positions in B-fragment fp16 layout.
// ---------------------------------------------------------------------------
__global__ __launch_bounds__(256) void prep_fused(const float* __restrict__ mem,
                                                  const float* __restrict__ img,
                                                  unsigned short* __restrict__ cmh,
                                                  float* __restrict__ hn,
                                                  unsigned int* __restrict__ hnb,
                                                  unsigned short* __restrict__ xh) {
    if (blockIdx.x >= 4096) {
        // ---- prep_x body ----
        const int t = (blockIdx.x - 4096) * 256 + threadIdx.x;   // 36864
        const int nl = t & 31, g = (t >> 5) & 1, ks = (t >> 6) & 3, pt = t >> 8;
        const int pos = pt * 32 + nl;
        const int u = ks * 2 + g;
        unsigned short h[8];
        if (pos < MCLS) {
            const int mr = pos / 67, mc = pos - mr * 67;
            const int r = mr - 5 + u;
            #pragma unroll
            for (int j = 0; j < 8; ++j) {
                const int c = mc - 5 + j;
                float v = 0.f;
                if ((unsigned)r < 64u && (unsigned)c < 64u) v = img[r * 64 + c];
                h[j] = f2h(v);
            }
        } else {
            #pragma unroll
            for (int j = 0; j < 8; ++j) h[j] = 0;
        }
        #pragma unroll
        for (int j = 0; j < 8; ++j) xh[(size_t)t * 8 + j] = h[j];
        return;
    }

    // ---- prep_cm body: one wave per n ----
    __shared__ float rowbuf[4][240];
    const int wave = threadIdx.x >> 6, lane = threadIdx.x & 63;
    const int n = blockIdx.x * 4 + wave;
    const float* mrow = mem + (size_t)n * MDIM;

    if (lane < 56) {
        const float4 v4 = *(const float4*)(mrow + lane * 4);
        *(float4*)(&rowbuf[wave][lane * 4]) = v4;
    } else if (lane == 56) {
        rowbuf[wave][224] = mrow[224];
    }
    // Same-wave LDS write->read: compiler inserts the lgkmcnt wait.

    const float* rb = rowbuf[wave];
    float q = 0.f;
    for (int t2 = lane; t2 < MDIM; t2 += 64) { const float v2 = rb[t2]; q += v2 * v2; }
    #pragma unroll
    for (int m = 1; m < 64; m <<= 1) q += __shfl_xor(q, m);
    if (lane == 0) {
        const float h = 0.5f * q;
        hn[n] = h;
        const unsigned short nh = f2h(-h);
        const unsigned short nl2 = f2h(-h - h2f(nh));
        hnb[n] = (unsigned)nh | ((unsigned)nl2 << 16);
    }

    const int k = lane, u = k >> 3, v = k & 7;
    const int ir = 2 * u, ic = 2 * v;
    float g9[3][3];
    #pragma unroll
    for (int di = -1; di <= 1; ++di) {
        #pragma unroll
        for (int dj = -1; dj <= 1; ++dj) {
            const int i = ir + di, j = ic + dj;
            g9[di + 1][dj + 1] = ((unsigned)i < 15u && (unsigned)j < 15u)
                                     ? rb[i * 15 + j] : 0.f;
        }
    }
    #pragma unroll
    for (int er = 0; er < 2; ++er) {
        #pragma unroll
        for (int ec = 0; ec < 2; ++ec) {
            const int cls = er * 2 + ec;
            float s = 0.f;
            s += g9[1 - er][1 - ec];
            s += g9[1 - er][2 - ec];
            s += g9[2 - er][1 - ec];
            s += g9[2 - er][2 - ec];
            cmh[((size_t)(cls * NMEM + n)) * 64 + k] = f2h(s);
        }
    }
}

// ---------------------------------------------------------------------------
// K1 (R10-exact, measured plateau 74-78us across 8 variants incl. identical
// code re-measured): fp16 single-product MFMA scoring. Grid (256 nblk, 4 cls),
// 4 waves, __launch_bounds__(256,4). A (64 n x 64 k) register-resident; -hn
// folded via fp16 hi/lo ext K-slice. B single-buffered (16 regs), prefetched
// right after MFMAs consume them (xh is L2-hot). No LDS, no barriers. Top-2
// via v_med3_f32 + hoisted idv table; cross-half merge via __shfl_xor.
//
// CLOSED LEVERS (all measured): op-count cuts neutral (R4); permlane slower
// (R6); (256,5) spills (R9: FETCH 395MB); +32-reg f32 C-init spills (R3:
// FETCH 610MB); z-split neutral (R8); phase stagger null (R11); cross-kernel
// fence fusion catastrophic (R12: +70us device-fence coherence cost).
//
// nblk XCD-write-merge swizzle: (bx&7)*32 + (bx>>3) -> same-XCD blocks own
// consecutive nblk so 8B float2 stores merge into full 64B lines in L2
// (verified R0->R1: WRITE_SIZE 158MB -> 36.9MB).
// A/B frag: row=lane&31, k=(lane>>5)*8+j. C/D: col=lane&31,
// row=(r&3)+8*(r>>2)+4*(lane>>5)  [HW-verified].
// ---------------------------------------------------------------------------
__global__ __launch_bounds__(256, 4) void mfma_argmin_kernel(const unsigned short* __restrict__ cmh,
                                                             const unsigned short* __restrict__ xh,
                                                             const unsigned int* __restrict__ hnb,
                                                             float* __restrict__ pcvT) {
    const int nblk = ((blockIdx.x & 7) << 5) | (blockIdx.x >> 3);   // XCD write-merge swizzle
    const int cls = blockIdx.y;
    const int t = threadIdx.x, wave = t >> 6, lane = t & 63;
    const int g = lane >> 5, nl = lane & 31;

    // One-time A fragment loads (row nl and nl+32, all 4 K-slices).
    f16x8 a0[4], a1[4];
    #pragma unroll
    for (int ks = 0; ks < 4; ++ks) {
        const size_t base = ((size_t)(cls * NMEM + nblk * 64 + nl)) * 64 + ks * 16 + g * 8;
        a0[ks] = *(const f16x8*)(cmh + base);
        a1[ks] = *(const f16x8*)(cmh + base + 32 * 64);
    }

    // hn-folding ext slice: A_ext=(-hn_hi,-hn_lo,0..), B_ext=(1,1,0..).
    const unsigned int hp0 = hnb[nblk * 64 + nl];
    const unsigned int hp1 = hnb[nblk * 64 + 32 + nl];
    f16x8 aex0 = {0,0,0,0,0,0,0,0}, aex1 = {0,0,0,0,0,0,0,0}, bex = {0,0,0,0,0,0,0,0};
    if (g == 0) {
        aex0[0] = us2h((unsigned short)(hp0 & 0xFFFFu));
        aex0[1] = us2h((unsigned short)(hp0 >> 16));
        aex1[0] = us2h((unsigned short)(hp1 & 0xFFFFu));
        aex1[1] = us2h((unsigned short)(hp1 >> 16));
        bex[0] = (_Float16)1.0f;
        bex[1] = (_Float16)1.0f;
    }

    // Hoisted id table: 16 VGPRs, loop-invariant.
    int idv[16];
    #pragma unroll
    for (int r = 0; r < 16; ++r) idv[r] = (r & 3) + 8 * (r >> 2) + 4 * g;

    // B pointer for this wave/g: pt = it*4+wave  =>  +8192 halves per iter.
    const unsigned short* xp = xh + ((size_t)((wave * 4) * 2 + g)) * 256 + nl * 8;

    // Store pointer: pos = (it*4+wave)*32 + nl advances 128/iter => +65536 f.
    float* stp = pcvT + ((size_t)(cls * PPAD + wave * 32 + nl)) * NTILE2 + nblk * 2;

    f16x8 b[4];
    #pragma unroll
    for (int ks = 0; ks < 4; ++ks) b[ks] = *(const f16x8*)(xp + ks * 512);

    for (int it = 0; it < 36; ++it) {
        f32x16 acc0 = {0.f,0.f,0.f,0.f,0.f,0.f,0.f,0.f,0.f,0.f,0.f,0.f,0.f,0.f,0.f,0.f};
        f32x16 acc1 = {0.f,0.f,0.f,0.f,0.f,0.f,0.f,0.f,0.f,0.f,0.f,0.f,0.f,0.f,0.f,0.f};
        __builtin_amdgcn_s_setprio(1);
        #pragma unroll
        for (int ks = 0; ks < 4; ++ks) {
            acc0 = __builtin_amdgcn_mfma_f32_32x32x16_f16(a0[ks], b[ks], acc0, 0, 0, 0);
            acc1 = __builtin_amdgcn_mfma_f32_32x32x16_f16(a1[ks], b[ks], acc1, 0, 0, 0);
        }
        acc0 = __builtin_amdgcn_mfma_f32_32x32x16_f16(aex0, bex, acc0, 0, 0, 0);
        acc1 = __builtin_amdgcn_mfma_f32_32x32x16_f16(aex1, bex, acc1, 0, 0, 0);
        __builtin_amdgcn_s_setprio(0);

        // Prefetch next B into the SAME registers (WAR-safe: MFMAs above
        // already consumed b). Epilogue below hides the load latency.
        xp += 8192;
        if (it < 35) {
            #pragma unroll
            for (int ks = 0; ks < 4; ++ks) b[ks] = *(const f16x8*)(xp + ks * 512);
        }

        // Exact top-2 insert: m2 = med3(m1_old, m2_old, v); m1 = max(m1_old, v).
        float m1 = -3.0e38f, m2 = -3.0e38f;
        #pragma unroll
        for (int r = 0; r < 16; ++r) {
            const float v = __int_as_float((__float_as_int(acc0[r]) & ~63) | idv[r]);
            m2 = __builtin_amdgcn_fmed3f(m1, m2, v);
            m1 = fmaxf(m1, v);
        }
        #pragma unroll
        for (int r = 0; r < 16; ++r) {
            const float w = __int_as_float(((__float_as_int(acc1[r]) & ~63) | idv[r]) | 32);
            m2 = __builtin_amdgcn_fmed3f(m1, m2, w);
            m1 = fmaxf(m1, w);
        }

        const float o1 = __shfl_xor(m1, 32);
        const float o2 = __shfl_xor(m2, 32);
        const float M1 = fmaxf(m1, o1);
        const float M2 = fmaxf(fminf(m1, o1), fmaxf(m2, o2));

        if (g == 0) {
            float2 st; st.x = M1; st.y = M2;
            *(float2*)stp = st;
        }
        stp += (size_t)128 * NTILE2;
    }
}

// ---------------------------------------------------------------------------
// K2: rescue, one wave per (cls, pos). Singleton fast-path (R8): tot==1
// recovers the winner directly from the packed 6-bit id (no mem reads, no
// reduces) — output identical. tot>=2 falls to the pair-pipelined
// exact-rescore loop.
// ---------------------------------------------------------------------------
__global__ __launch_bounds__(256) void rescue_kernel(const float* __restrict__ img,
                                                     const float* __restrict__ mem,
                                                     const float* __restrict__ hn,
                                                     const float* __restrict__ pcvT,
                                                     int* __restrict__ idx2d) {
    const int wave = threadIdx.x >> 6, lane = threadIdx.x & 63;
    const int cls = blockIdx.y;
    const int pos = blockIdx.x * 4 + wave;
    if (pos >= MCLS) return;
    const int er = cls >> 1, ec = cls & 1;
    const int mr = pos / 67, mc = pos - mr * 67;

    const float* row = pcvT + ((size_t)(cls * PPAD + pos)) * NTILE2 + lane * 8;
    const float4 v0 = *(const float4*)row;
    const float4 v1 = *(const float4*)(row + 4);
    float vals[8] = {v0.x, v0.y, v0.z, v0.w, v1.x, v1.y, v1.z, v1.w};

    float vmax = vals[0];
    #pragma unroll
    for (int s = 1; s < 8; ++s) vmax = fmaxf(vmax, vals[s]);
    #pragma unroll
    for (int m = 1; m < 64; m <<= 1) vmax = fmaxf(vmax, __shfl_xor(vmax, m));
    const float thr = vmax - MARGIN;

    unsigned long long bals[8];
    int tot = 0;
    #pragma unroll
    for (int s = 0; s < 8; ++s) {
        bals[s] = __ballot(vals[s] >= thr);
        tot += __popcll(bals[s]);
    }

    int bn = 0x7FFFFFFF;
    if (tot == 1) {
        float cv = -3.0e38f; int cs = 0;
        #pragma unroll
        for (int s = 0; s < 8; ++s)
            if (vals[s] >= thr) { cv = vals[s]; cs = s; }
        unsigned long long ba = 0;
        #pragma unroll
        for (int s = 0; s < 8; ++s) ba |= bals[s];
        const int src = __ffsll((long long)ba) - 1;
        const float pv = __shfl(cv, src);
        const int ss = __shfl(cs, src);
        bn = (((src * 8 + ss) >> 1) << 6) | (__float_as_int(pv) & 63);
    } else {
        const int xr = mr - 5 + (lane >> 3), xc = mc - 5 + (lane & 7);
        const float xv = ((unsigned)xr < 64u && (unsigned)xc < 64u) ? img[xr * 64 + xc] : 0.f;
        float xt[4];
        #pragma unroll
        for (int q = 0; q < 4; ++q) {
            const int tt = q * 64 + lane;
            const int a = tt / 15, b = tt - 15 * a;
            const int xi = (((a + er) >> 1) & 7) * 8 + (((b + ec) >> 1) & 7);
            xt[q] = __shfl(xv, xi);
        }

        float best = -3.0e38f;
        #pragma unroll
        for (int s = 0; s < 8; ++s) {
            unsigned long long bal = bals[s];
            while (bal) {
                const int src0 = __ffsll((long long)bal) - 1;
                bal &= bal - 1;
                int src1 = -1;
                if (bal) { src1 = __ffsll((long long)bal) - 1; bal &= bal - 1; }
                const float pv0 = __shfl(vals[s], src0);
                const float pv1 = __shfl(vals[s], src1 < 0 ? src0 : src1);
                const int n0 = (((src0 * 8 + s) >> 1) << 6) | (__float_as_int(pv0) & 63);
                const int n1 = ((((src1 < 0 ? src0 : src1) * 8 + s) >> 1) << 6) | (__float_as_int(pv1) & 63);
                const float* mrow0 = mem + (size_t)n0 * MDIM;
                const float* mrow1 = mem + (size_t)n1 * MDIM;
                float p0 = 0.f, p1 = 0.f;
                #pragma unroll
                for (int q = 0; q < 4; ++q) {
                    const int tt = q * 64 + lane;
                    if (tt < MDIM) {
                        p0 = fmaf(mrow0[tt], xt[q], p0);
                        p1 = fmaf(mrow1[tt], xt[q], p1);
                    }
                }
                #pragma unroll
                for (int m = 1; m < 64; m <<= 1) {
                    p0 += __shfl_xor(p0, m);
                    p1 += __shfl_xor(p1, m);
                }
                const float sc0 = p0 - hn[n0];
                if (sc0 > best || (sc0 == best && n0 < bn)) { best = sc0; bn = n0; }
                if (src1 >= 0) {
                    const float sc1 = p1 - hn[n1];
                    if (sc1 > best || (sc1 == best && n1 < bn)) { best = sc1; bn = n1; }
                }
            }
        }
    }
    if (lane == 0) idx2d[(er + 2 * mr) * L1D + (ec + 2 * mc)] = bn;
}

// ---------------------------------------------------------------------------
// K3: fold, one wave per output pixel. (R12 lesson: do NOT fuse norm via
// last-block + device fences — per-block __threadfence costs ~70us on
// non-coherent XCD L2s. Separate launches are cheaper.)
// ---------------------------------------------------------------------------
__global__ __launch_bounds__(256) void fold_kernel(const float* __restrict__ mem,
                                                   const int* __restrict__ idx2d,
                                                   float* __restrict__ outraw) {
    const int wave = threadIdx.x >> 6, lane = threadIdx.x & 63;
    const int p = blockIdx.x * 4 + wave;   // 0..4095
    const int oi = p >> 6, oj = p & 63;
    float s = 0.f;
    #pragma unroll
    for (int tb = 0; tb < 256; tb += 64) {
        const int tt = tb + lane;
        if (tt < MDIM) {
            const int a = tt / 15, b = tt - 15 * a;
            const int r = 10 + 2 * oi - a, c = 10 + 2 * oj - b;
            if ((unsigned)r < (unsigned)L1D && (unsigned)c < (unsigned)L1D) {
                const int n = idx2d[r * L1D + c];
                s += mem[(size_t)n * MDIM + tt];
            }
        }
    }
    #pragma unroll
    for (int msk = 1; msk < 64; msk <<= 1) s += __shfl_xor(s, msk);
    if (lane == 0) outraw[p] = s;
}

// ---------------------------------------------------------------------------
// K4: divide by global max (single block).
// ---------------------------------------------------------------------------
__global__ __launch_bounds__(256) void norm_kernel(const float* __restrict__ outraw,
                                                   float* __restrict__ out) {
    __shared__ float red[256];
    const int t = threadIdx.x;
    float m = -3.0e38f;
    #pragma unroll
    for (int i = 0; i < 16; ++i) m = fmaxf(m, outraw[t + i * 256]);
    red[t] = m;
    __syncthreads();
    for (int s = 128; s > 0; s >>= 1) {
        if (t < s) red[t] = fmaxf(red[t], red[t + s]);
        __syncthreads();
    }
    const float mx = red[0];
    #pragma unroll
    for (int i = 0; i < 16; ++i) out[t + i * 256] = outraw[t + i * 256] / mx;
}

extern "C" void kernel_launch(void* const* d_in, const int* in_sizes, int n_in,
                              void* d_out, int out_size, void* d_ws, size_t ws_size,
                              hipStream_t stream) {
    const float* img = (const float*)d_in[0];   // 64*64 fp32
    const float* mem = (const float*)d_in[1];   // 16384*225 fp32
    float* out = (float*)d_out;                 // 4096 fp32

    unsigned short* cmh = (unsigned short*)d_ws;              // 4*16384*64 ushort = 8.4 MB
    float* hn = (float*)(cmh + (size_t)4 * NMEM * 64);        // 16384 f
    unsigned int* hnb = (unsigned int*)(hn + NMEM);           // 16384 u32
    unsigned short* xh = (unsigned short*)(hnb + NMEM);       // 294912 ushort
    float* pcvT = (float*)(xh + 294912);                      // 4*4608*512 f = 37.7 MB
    int* idx2d = (int*)(pcvT + (size_t)4 * PPAD * NTILE2);    // 17956 i
    float* outraw = (float*)(idx2d + L1D * L1D);              // 4096 f

    prep_fused<<<4096 + 144, 256, 0, stream>>>(mem, img, cmh, hn, hnb, xh);
    mfma_argmin_kernel<<<dim3(256, 4), 256, 0, stream>>>(cmh, xh, hnb, pcvT);
    rescue_kernel<<<dim3((MCLS + 3) / 4, 4), 256, 0, stream>>>(img, mem, hn, pcvT, idx2d);
    fold_kernel<<<1024, 256, 0, stream>>>(mem, idx2d, outraw);
    norm_kernel<<<1, 256, 0, stream>>>(outraw, out);
}